// Round 1
// baseline (781.127 us; speedup 1.0000x reference)
//
#include <hip/hip_runtime.h>
#include <hip/hip_bf16.h>
#include <stdint.h>

typedef __bf16 bf16;
typedef __bf16 bf16x8 __attribute__((ext_vector_type(8)));
typedef __bf16 bf16x4 __attribute__((ext_vector_type(4)));
typedef float f32x4 __attribute__((ext_vector_type(4)));

static constexpr int BATCH = 4;
static constexpr int CH    = 512;   // input channels
static constexpr int HH    = 64;
static constexpr int WW    = 80;
static constexpr int NSPAT = HH * WW;       // 5120
static constexpr int KCH   = 256;           // key/query channels
static constexpr int VCH   = 512;           // value channels
static constexpr int HPAD  = HH + 2;        // 66
static constexpr int WPAD  = WW + 2;        // 82
static constexpr int NPAD  = HPAD * WPAD;   // 5412
static constexpr float BN_EPS = 1e-5f;

enum { MODE_LIN = 0, MODE_PAD = 1, MODE_CONV = 2, MODE_SIMF32 = 3 };
enum { EPI_KF = 0, EPI_S = 1, EPI_V1 = 2, EPI_V = 3, EPI_CTX = 4 };

__device__ __forceinline__ void gll16(const void* g, void* l) {
  __builtin_amdgcn_global_load_lds((const __attribute__((address_space(1))) void*)g,
                                   (__attribute__((address_space(3))) void*)l,
                                   16, 0, 0);
}

// C[M,N] = A[M,K] * B[N,K]^T  (both row-major over K), bf16 inputs, fp32 acc.
// 128x128 tile, BK=32, 4 waves (2x2 of 64x64), mfma_f32_16x16x32_bf16.
template<int MODE, int EPI, int KDIM>
__global__ __launch_bounds__(256)
void k_gemm(const bf16* __restrict__ Ag, const void* __restrict__ Bg,
            void* __restrict__ Og, const float* __restrict__ ep0,
            const float* __restrict__ ep1,
            long Astr, long Bstr, long Ostr) {
  __shared__ bf16 As[128 * 32];
  __shared__ bf16 Bs[128 * 32];
  const int tid  = threadIdx.x;
  const int wave = tid >> 6;
  const int lane = tid & 63;
  const int n0 = blockIdx.x * 128;
  const int m0 = blockIdx.y * 128;
  const int b  = blockIdx.z;

  // staging geometry: per wave 2 issues x 16 rows, lane covers row=base+l/4, col=(l%4)*8
  const int colo = (tid & 3) * 8;
  const int r0   = wave * 32 + (lane >> 2);
  const int r1   = r0 + 16;

  const bf16* Ab  = Ag + (long)b * Astr;
  const bf16* ag0 = Ab + (long)(m0 + r0) * KDIM + colo;
  const bf16* ag1 = Ab + (long)(m0 + r1) * KDIM + colo;
  bf16* al0 = As + wave * 1024;
  bf16* al1 = As + wave * 1024 + 512;
  bf16* bl0 = Bs + wave * 1024;
  bf16* bl1 = Bs + wave * 1024 + 512;

  const bf16*  BbB = (const bf16*)Bg + (long)b * Bstr;
  const float* Sg  = (const float*)Bg + (long)b * Bstr;
  const bf16* bg0 = nullptr;
  const bf16* bg1 = nullptr;
  int bsp0 = 0, bsp1 = 0;
  if constexpr (MODE == MODE_LIN) {
    bg0 = BbB + (long)(n0 + r0) * KDIM + colo;
    bg1 = BbB + (long)(n0 + r1) * KDIM + colo;
  } else if constexpr (MODE == MODE_PAD) {
    const int na = n0 + r0, nb = n0 + r1;
    bg0 = BbB + ((long)((na / WW + 1) * WPAD + (na % WW) + 1)) * CH + colo;
    bg1 = BbB + ((long)((nb / WW + 1) * WPAD + (nb % WW) + 1)) * CH + colo;
  } else if constexpr (MODE == MODE_CONV) {
    const int na = n0 + r0, nb = n0 + r1;
    bsp0 = (na / WW) * WPAD + (na % WW);
    bsp1 = (nb / WW) * WPAD + (nb % WW);
  }

  f32x4 acc[4][4] = {};

  const int wm = wave >> 1, wn = wave & 1;
  const int fr = lane & 15;
  const int k8 = (lane >> 4) * 8;
  const bf16* ArF = As + (wm * 64 + fr) * 32 + k8;
  const bf16* BrF = Bs + (wn * 64 + fr) * 32 + k8;

  for (int k0 = 0; k0 < KDIM; k0 += 32) {
    gll16(ag0 + k0, al0);
    gll16(ag1 + k0, al1);
    if constexpr (MODE == MODE_LIN || MODE == MODE_PAD) {
      gll16(bg0 + k0, bl0);
      gll16(bg1 + k0, bl1);
    } else if constexpr (MODE == MODE_CONV) {
      const int tap    = k0 >> 9;      // 512 channels per tap
      const int within = k0 & 511;
      const int kh  = tap / 3;
      const int kw  = tap - kh * 3;
      const int off = kh * WPAD + kw;
      gll16(BbB + (long)(bsp0 + off) * CH + within + colo, bl0);
      gll16(BbB + (long)(bsp1 + off) * CH + within + colo, bl1);
    } else { // MODE_SIMF32: reg-stage fp32 sim -> bf16 LDS
      #pragma unroll
      for (int p = 0; p < 4; ++p) {
        const int idx = p * 256 + tid;
        const int rr  = idx >> 3;
        const int cg  = (idx & 7) * 4;
        const float4 f = *(const float4*)(Sg + (long)(n0 + rr) * NSPAT + k0 + cg);
        bf16x4 hq;
        hq[0] = (bf16)f.x; hq[1] = (bf16)f.y; hq[2] = (bf16)f.z; hq[3] = (bf16)f.w;
        *(bf16x4*)(Bs + rr * 32 + cg) = hq;
      }
    }
    __syncthreads();
    bf16x8 af[4], bfv[4];
    #pragma unroll
    for (int i = 0; i < 4; ++i) af[i] = *(const bf16x8*)(ArF + i * 16 * 32);
    #pragma unroll
    for (int j = 0; j < 4; ++j) bfv[j] = *(const bf16x8*)(BrF + j * 16 * 32);
    #pragma unroll
    for (int i = 0; i < 4; ++i)
      #pragma unroll
      for (int j = 0; j < 4; ++j)
        acc[i][j] = __builtin_amdgcn_mfma_f32_16x16x32_bf16(af[i], bfv[j], acc[i][j], 0, 0, 0);
    __syncthreads();
  }

  const int row0 = m0 + wm * 64 + (lane >> 4) * 4;  // M index (+i*16+r)
  const int col0 = n0 + wn * 64 + (lane & 15);      // N index (+j*16)

  if constexpr (EPI == EPI_KF || EPI == EPI_V1) {
    // write TRANSPOSED (out[n][m]) bf16, 4 consecutive m per lane -> 8B stores
    constexpr int LDO = (EPI == EPI_KF) ? KCH : VCH;
    bf16* op = (bf16*)Og + (long)b * Ostr;
    #pragma unroll
    for (int i = 0; i < 4; ++i) {
      const int m = row0 + i * 16;
      float sc[4], bi[4];
      #pragma unroll
      for (int r = 0; r < 4; ++r) {
        if constexpr (EPI == EPI_KF) { sc[r] = ep0[m + r]; bi[r] = ep1[m + r]; }
        else                         { sc[r] = 1.0f;       bi[r] = ep0[m + r]; }
      }
      #pragma unroll
      for (int j = 0; j < 4; ++j) {
        const int n = col0 + j * 16;
        bf16x4 pk;
        #pragma unroll
        for (int r = 0; r < 4; ++r)
          pk[r] = (bf16)fmaxf(acc[i][j][r] * sc[r] + bi[r], 0.0f);
        *(bf16x4*)(op + (long)n * LDO + m) = pk;
      }
    }
  } else if constexpr (EPI == EPI_S) {
    float* op = (float*)Og + (long)b * Ostr;
    #pragma unroll
    for (int i = 0; i < 4; ++i)
      #pragma unroll
      for (int r = 0; r < 4; ++r) {
        const long base = (long)(row0 + i * 16 + r) * NSPAT;
        #pragma unroll
        for (int j = 0; j < 4; ++j)
          op[base + col0 + j * 16] = acc[i][j][r] * 0.0625f;  // * KC^-0.5
      }
  } else if constexpr (EPI == EPI_V) {
    bf16* op = (bf16*)Og + (long)b * Ostr;   // v[m][n] row-major
    #pragma unroll
    for (int i = 0; i < 4; ++i)
      #pragma unroll
      for (int r = 0; r < 4; ++r) {
        const int m = row0 + i * 16 + r;
        const float bi = ep0[m];
        #pragma unroll
        for (int j = 0; j < 4; ++j)
          op[(long)m * NSPAT + col0 + j * 16] = (bf16)fmaxf(acc[i][j][r] + bi, 0.0f);
      }
  } else { // EPI_CTX
    float* op = (float*)Og + (long)b * Ostr;
    #pragma unroll
    for (int i = 0; i < 4; ++i)
      #pragma unroll
      for (int r = 0; r < 4; ++r) {
        const long base = (long)(row0 + i * 16 + r) * NSPAT;
        #pragma unroll
        for (int j = 0; j < 4; ++j)
          op[base + col0 + j * 16] = acc[i][j][r];
      }
  }
}

// x [B][C][H][W] f32  ->  xpadT [B][NPAD][C] bf16 (zero-padded spatial, channel-contig)
__global__ __launch_bounds__(256)
void k_xpad(const float* __restrict__ x, bf16* __restrict__ xp) {
  __shared__ float t[64 * 81];
  const int cb  = blockIdx.x;   // 8 blocks of 64 channels
  const int h   = blockIdx.y;
  const int b   = blockIdx.z;
  const int tid = threadIdx.x;
  const float* xb = x + ((long)b * CH + cb * 64) * NSPAT + h * WW;
  for (int idx = tid; idx < 64 * 80; idx += 256) {
    const int cl = idx / 80;
    const int w  = idx - cl * 80;
    t[cl * 81 + w] = xb[(long)cl * NSPAT + w];
  }
  __syncthreads();
  bf16* op = xp + ((long)b * NPAD + (long)(h + 1) * WPAD + 1) * CH + cb * 64;
  for (int idx = tid; idx < 80 * 64; idx += 256) {
    const int w  = idx >> 6;
    const int cl = idx & 63;
    op[(long)w * CH + cl] = (bf16)t[cl * 81 + w];
  }
}

__global__ void k_cvt(const float* __restrict__ in, bf16* __restrict__ out, int n) {
  const int i = blockIdx.x * 256 + threadIdx.x;
  if (i < n) out[i] = (bf16)in[i];
}

// wv1 [VC][C][3][3] f32 -> wv1b [VC][9][C] bf16  (tap-major K so conv taps are K-contig)
__global__ void k_cvt_wv1(const float* __restrict__ in, bf16* __restrict__ out) {
  const int o   = blockIdx.x * 256 + threadIdx.x;
  const int c   = o & 511;
  const int t2  = o >> 9;
  const int tap = t2 % 9;
  const int vc  = t2 / 9;
  out[o] = (bf16)in[((long)vc * 512 + c) * 9 + tap];
}

__global__ void k_bnp(const float* bk, const float* gamma, const float* beta,
                      const float* rmean, const float* rvar,
                      float* s, float* t) {
  const int k = threadIdx.x;
  const float sc = gamma[k] / sqrtf(rvar[k] + BN_EPS);
  s[k] = sc;
  t[k] = (bk[k] - rmean[k]) * sc + beta[k];
}

// one block per row: softmax over 5120 f32 in place; optional bf16 copy
__global__ __launch_bounds__(256)
void k_softmax(float* __restrict__ S, bf16* __restrict__ outb) {
  const int tid = threadIdx.x;
  float* p = S + (long)blockIdx.x * NSPAT;
  float4 v[5];
  float mx = -3.0e38f;
  #pragma unroll
  for (int q = 0; q < 5; ++q) {
    v[q] = *(const float4*)(p + (q * 256 + tid) * 4);
    mx = fmaxf(mx, fmaxf(fmaxf(v[q].x, v[q].y), fmaxf(v[q].z, v[q].w)));
  }
  __shared__ float red[4];
  #pragma unroll
  for (int o = 32; o > 0; o >>= 1) mx = fmaxf(mx, __shfl_xor(mx, o));
  if ((tid & 63) == 0) red[tid >> 6] = mx;
  __syncthreads();
  mx = fmaxf(fmaxf(red[0], red[1]), fmaxf(red[2], red[3]));
  float sum = 0.0f;
  #pragma unroll
  for (int q = 0; q < 5; ++q) {
    v[q].x = __expf(v[q].x - mx);
    v[q].y = __expf(v[q].y - mx);
    v[q].z = __expf(v[q].z - mx);
    v[q].w = __expf(v[q].w - mx);
    sum += (v[q].x + v[q].y) + (v[q].z + v[q].w);
  }
  #pragma unroll
  for (int o = 32; o > 0; o >>= 1) sum += __shfl_xor(sum, o);
  __syncthreads();
  if ((tid & 63) == 0) red[tid >> 6] = sum;
  __syncthreads();
  sum = (red[0] + red[1]) + (red[2] + red[3]);
  const float inv = 1.0f / sum;
  bf16* ob = outb ? outb + (long)blockIdx.x * NSPAT : nullptr;
  #pragma unroll
  for (int q = 0; q < 5; ++q) {
    float4 o4;
    o4.x = v[q].x * inv; o4.y = v[q].y * inv;
    o4.z = v[q].z * inv; o4.w = v[q].w * inv;
    *(float4*)(p + (q * 256 + tid) * 4) = o4;
    if (outb) {
      bf16x4 hb;
      hb[0] = (bf16)o4.x; hb[1] = (bf16)o4.y; hb[2] = (bf16)o4.z; hb[3] = (bf16)o4.w;
      *(bf16x4*)(ob + (q * 256 + tid) * 4) = hb;
    }
  }
}

extern "C" void kernel_launch(void* const* d_in, const int* in_sizes, int n_in,
                              void* d_out, int out_size, void* d_ws, size_t ws_size,
                              hipStream_t stream) {
  const float* x     = (const float*)d_in[0];
  const float* wk    = (const float*)d_in[1];
  const float* bk    = (const float*)d_in[2];
  const float* gamma = (const float*)d_in[3];
  const float* beta  = (const float*)d_in[4];
  const float* rmean = (const float*)d_in[5];
  const float* rvar  = (const float*)d_in[6];
  const float* wv1   = (const float*)d_in[7];
  const float* bv1   = (const float*)d_in[8];
  const float* wv2   = (const float*)d_in[9];
  const float* bv2   = (const float*)d_in[10];

  float* ctx = (float*)d_out;                    // [B][VC][N]
  float* Sb  = ctx + (long)BATCH * VCH * NSPAT;  // [B][N][N]

  char* w = (char*)d_ws;
  auto alloc = [&](size_t bytes) {
    char* r = w;
    w += (bytes + 255) & ~(size_t)255;
    return r;
  };
  bf16*  xpadT = (bf16*)alloc((size_t)BATCH * NPAD * CH * 2);
  bf16*  kfT   = (bf16*)alloc((size_t)BATCH * NSPAT * KCH * 2);
  bf16*  v1T   = (bf16*)alloc((size_t)BATCH * NSPAT * VCH * 2);
  bf16*  vB    = (bf16*)alloc((size_t)BATCH * VCH * NSPAT * 2);
  bf16*  wkb   = (bf16*)alloc((size_t)KCH * CH * 2);
  bf16*  wv1b  = (bf16*)alloc((size_t)VCH * CH * 9 * 2);
  bf16*  wv2b  = (bf16*)alloc((size_t)VCH * VCH * 2);
  float* bnS   = (float*)alloc(KCH * 4);
  float* bnT   = (float*)alloc(KCH * 4);
  const size_t used = (size_t)(w - (char*)d_ws);
  if (ws_size < used) return;  // cannot compute without minimal workspace
  bf16* simb = nullptr;
  const size_t simbytes = (size_t)BATCH * NSPAT * NSPAT * 2;
  if (ws_size >= used + simbytes) simb = (bf16*)w;

  hipMemsetAsync(xpadT, 0, (size_t)BATCH * NPAD * CH * 2, stream);
  k_xpad<<<dim3(8, HH, BATCH), 256, 0, stream>>>(x, xpadT);
  k_cvt<<<(KCH * CH) / 256, 256, 0, stream>>>(wk, wkb, KCH * CH);
  k_cvt_wv1<<<(VCH * CH * 9) / 256, 256, 0, stream>>>(wv1, wv1b);
  k_cvt<<<(VCH * VCH) / 256, 256, 0, stream>>>(wv2, wv2b, VCH * VCH);
  k_bnp<<<1, KCH, 0, stream>>>(bk, gamma, beta, rmean, rvar, bnS, bnT);

  // G1: kfT[b][n][kc] = relu(bn(wk . x))
  k_gemm<MODE_PAD, EPI_KF, CH><<<dim3(NSPAT / 128, KCH / 128, BATCH), 256, 0, stream>>>(
      wkb, xpadT, kfT, bnS, bnT, 0, (long)NPAD * CH, (long)NSPAT * KCH);
  // G2: S[b][n][m] = kf_n . kf_m / 16
  k_gemm<MODE_LIN, EPI_S, KCH><<<dim3(NSPAT / 128, NSPAT / 128, BATCH), 256, 0, stream>>>(
      kfT, kfT, Sb, nullptr, nullptr, (long)NSPAT * KCH, (long)NSPAT * KCH, (long)NSPAT * NSPAT);
  // G3: v1T[b][n][vc] = relu(conv3x3(x))  (K = 9 taps x 512 ch over padded x)
  k_gemm<MODE_CONV, EPI_V1, CH * 9><<<dim3(NSPAT / 128, VCH / 128, BATCH), 256, 0, stream>>>(
      wv1b, xpadT, v1T, bv1, nullptr, 0, (long)NPAD * CH, (long)NSPAT * VCH);
  // G4: v[b][vc][n] = relu(wv2 . v1)
  k_gemm<MODE_LIN, EPI_V, VCH><<<dim3(NSPAT / 128, VCH / 128, BATCH), 256, 0, stream>>>(
      wv2b, v1T, vB, bv2, nullptr, 0, (long)NSPAT * VCH, (long)VCH * NSPAT);
  // softmax rows of S (in place, fp32) + optional bf16 copy for G5
  k_softmax<<<BATCH * NSPAT, 256, 0, stream>>>(Sb, simb);
  // G5: context[b][vc][n] = sum_m v[vc][m] * sim[n][m]
  if (simb) {
    k_gemm<MODE_LIN, EPI_CTX, NSPAT><<<dim3(NSPAT / 128, VCH / 128, BATCH), 256, 0, stream>>>(
        vB, simb, ctx, nullptr, nullptr, (long)VCH * NSPAT, (long)NSPAT * NSPAT, (long)VCH * NSPAT);
  } else {
    k_gemm<MODE_SIMF32, EPI_CTX, NSPAT><<<dim3(NSPAT / 128, VCH / 128, BATCH), 256, 0, stream>>>(
        vB, Sb, ctx, nullptr, nullptr, (long)VCH * NSPAT, (long)NSPAT * NSPAT, (long)VCH * NSPAT);
  }
}